// Round 4
// baseline (117.959 us; speedup 1.0000x reference)
//
#include <hip/hip_runtime.h>
#include <math.h>

#define BB 16
#define CC 8
#define HH 512
#define WW 512
#define SLICES (BB*CC)                       // 128
#define SLICE_ELEMS (HH*WW)                  // 262144
#define BLOCKS_PER_SLICE 16
#define CHUNK (SLICE_ELEMS/BLOCKS_PER_SLICE) // 16384 elements
#define NBLOCKS (SLICES*BLOCKS_PER_SLICE)    // 2048
#define NTHREADS 256
#define TOTAL_N ((long long)SLICES*SLICE_ELEMS) // 33554432

// ws layout: double partial[2048] | int pc[2048] | int pr[2048] | int pcol[2048] | uint ticket
#define WS_PARTIAL_OFF   0
#define WS_PC_BYTE_OFF   (NBLOCKS * (int)sizeof(double))                 // 16384
#define WS_PR_BYTE_OFF   (WS_PC_BYTE_OFF + NBLOCKS * (int)sizeof(int))
#define WS_PCOL_BYTE_OFF (WS_PR_BYTE_OFF + NBLOCKS * (int)sizeof(int))
#define WS_TICKET_OFF    (WS_PCOL_BYTE_OFF + NBLOCKS * (int)sizeof(int)) // 40960

#define LOG2E 1.44269504088896340736f
#define LN2   0.69314718055994530942f

__device__ __forceinline__ float softplus_term(float x) {
    // max(x,0) + log1p(exp(-|x|)) = max(x,0) + ln2 * log2(1 + exp2(-|x| * log2e))
    float a = fabsf(x);
    float t = __builtin_amdgcn_exp2f(-a * LOG2E);   // v_exp_f32
    float l = __builtin_amdgcn_logf(1.0f + t);      // v_log_f32 (log2)
    return fmaxf(x, 0.0f) + LN2 * l;
}

__global__ __launch_bounds__(NTHREADS) void pil_main(
    const float* __restrict__ logits,
    const float* __restrict__ mask,
    double* __restrict__ partial,
    int* __restrict__ pc, int* __restrict__ pr, int* __restrict__ pcol,
    unsigned int* __restrict__ ticket,
    float* __restrict__ out)
{
    const int blk      = blockIdx.x;
    const int slice    = blk / BLOCKS_PER_SLICE;
    const int subchunk = blk % BLOCKS_PER_SLICE;
    const int chunkStartInSlice = subchunk * CHUNK;
    const long long base = (long long)slice * SLICE_ELEMS + chunkStartInSlice;
    const int tid = threadIdx.x;

    const float4* m4 = reinterpret_cast<const float4*>(mask + base);
    const float4* x4 = reinterpret_cast<const float4*>(logits + base);

    int    c_loc = 0, r_loc = 0, col_loc = 0;
    double s_loc = 0.0;

    // CHUNK/4 = 4096 float4 per block; unroll x4: 8 float4 loads in flight
    for (int i0 = tid; i0 < CHUNK / 4; i0 += 4 * NTHREADS) {
        float4 ma = m4[i0];
        float4 mb = m4[i0 + NTHREADS];
        float4 mc = m4[i0 + 2 * NTHREADS];
        float4 md = m4[i0 + 3 * NTHREADS];
        float4 xa = x4[i0];
        float4 xb = x4[i0 + NTHREADS];
        float4 xc = x4[i0 + 2 * NTHREADS];
        float4 xd = x4[i0 + 3 * NTHREADS];

        #pragma unroll
        for (int u = 0; u < 4; ++u) {
            float4 m = (u == 0) ? ma : (u == 1) ? mb : (u == 2) ? mc : md;
            float4 x = (u == 0) ? xa : (u == 1) ? xb : (u == 2) ? xc : xd;
            int i = i0 + u * NTHREADS;
            int eInSlice = chunkStartInSlice + i * 4;   // first of the 4 elements
            int row = eInSlice >> 9;                    // /512 (same row for all 4)
            int col = eInSlice & 511;

            int m0 = (m.x != 0.0f);
            int m1 = (m.y != 0.0f);
            int m2 = (m.z != 0.0f);
            int m3 = (m.w != 0.0f);
            int msum = m0 + m1 + m2 + m3;
            c_loc   += msum;
            r_loc   += row * msum;
            col_loc += col * msum + m1 + 2 * m2 + 3 * m3;

            float f = softplus_term(x.x) + softplus_term(x.y)
                    + softplus_term(x.z) + softplus_term(x.w);
            s_loc += (double)f;
        }
    }

    // wave-level reduce (64 lanes)
    for (int off = 32; off > 0; off >>= 1) {
        c_loc   += __shfl_down(c_loc,   off);
        r_loc   += __shfl_down(r_loc,   off);
        col_loc += __shfl_down(col_loc, off);
        s_loc   += __shfl_down(s_loc,   off);
    }

    __shared__ int    sc[NTHREADS / 64], sr[NTHREADS / 64], scol[NTHREADS / 64];
    __shared__ double sd[NTHREADS / 64];
    __shared__ int    isLast;
    const int wave = tid >> 6;
    const int lane = tid & 63;
    if (lane == 0) { sc[wave] = c_loc; sr[wave] = r_loc; scol[wave] = col_loc; sd[wave] = s_loc; }
    __syncthreads();

    if (tid == 0) {
        int    bc = 0, br = 0, bcol = 0;
        double bs = 0.0;
        #pragma unroll
        for (int w = 0; w < NTHREADS / 64; ++w) { bc += sc[w]; br += sr[w]; bcol += scol[w]; bs += sd[w]; }
        pc[blk]      = bc;
        pr[blk]      = br;
        pcol[blk]    = bcol;
        partial[blk] = bs;
        __threadfence();                                   // release: publish slots
        unsigned int old = atomicAdd(ticket, 1u);          // device-scope
        isLast = (old == (unsigned int)(NBLOCKS - 1));
    }
    __syncthreads();

    if (!isLast) return;

    // ---- last-arriving block: final reduction (previously pil_final) ----
    __threadfence();                                       // acquire: see all slots

    __shared__ double sdata[NTHREADS];
    double s = 0.0;
    for (int i = tid; i < NBLOCKS; i += NTHREADS) s += partial[i];

    if (tid < SLICES) {
        int c = 0, r = 0, cl = 0;
        #pragma unroll
        for (int k = 0; k < BLOCKS_PER_SLICE; ++k) {
            int idx = tid * BLOCKS_PER_SLICE + k;
            c  += pc[idx];
            r  += pr[idx];
            cl += pcol[idx];
        }
        if (c > 0) {
            // match reference: f32 divide then truncate toward zero
            int mr = (int)((float)r  / (float)c);
            int mc = (int)((float)cl / (float)c);
            s -= (double)logits[(long long)tid * SLICE_ELEMS + (long long)mr * WW + mc];
        }
    }

    sdata[tid] = s;
    __syncthreads();
    for (int stride = NTHREADS / 2; stride > 0; stride >>= 1) {
        if (tid < stride) sdata[tid] += sdata[tid + stride];
        __syncthreads();
    }
    if (tid == 0) out[0] = (float)(sdata[0] / (double)TOTAL_N);
}

extern "C" void kernel_launch(void* const* d_in, const int* in_sizes, int n_in,
                              void* d_out, int out_size, void* d_ws, size_t ws_size,
                              hipStream_t stream)
{
    const float* logits = (const float*)d_in[0];
    const float* mask   = (const float*)d_in[1];
    float* out = (float*)d_out;

    double*       partial = (double*)((char*)d_ws + WS_PARTIAL_OFF);
    int*          pc      = (int*)((char*)d_ws + WS_PC_BYTE_OFF);
    int*          pr      = (int*)((char*)d_ws + WS_PR_BYTE_OFF);
    int*          pcol    = (int*)((char*)d_ws + WS_PCOL_BYTE_OFF);
    unsigned int* ticket  = (unsigned int*)((char*)d_ws + WS_TICKET_OFF);

    // reset the ticket each call (memset node is cheaper than a kernel dispatch)
    hipMemsetAsync(ticket, 0, sizeof(unsigned int), stream);

    pil_main<<<NBLOCKS, NTHREADS, 0, stream>>>(logits, mask, partial, pc, pr, pcol, ticket, out);
}

// Round 5
// 49.210 us; speedup vs baseline: 2.3971x; 2.3971x over previous
//
#include <hip/hip_runtime.h>
#include <math.h>

#define BB 16
#define CC 8
#define HH 512
#define WW 512
#define SLICES (BB*CC)                       // 128
#define SLICE_ELEMS (HH*WW)                  // 262144
#define BLOCKS_PER_SLICE 16
#define CHUNK (SLICE_ELEMS/BLOCKS_PER_SLICE) // 16384 elements
#define NBLOCKS (SLICES*BLOCKS_PER_SLICE)    // 2048
#define NTHREADS 256
#define FTHREADS 512
#define TOTAL_N ((long long)SLICES*SLICE_ELEMS) // 33554432

// ws layout (all per-block slots, fully rewritten every call -> no memset):
//   double partial[2048] | int pc[2048] | int pr[2048] | int pcol[2048]
#define WS_PARTIAL_OFF 0
#define WS_PC_BYTE_OFF   (NBLOCKS * (int)sizeof(double))                  // 16384
#define WS_PR_BYTE_OFF   (WS_PC_BYTE_OFF + NBLOCKS * (int)sizeof(int))
#define WS_PCOL_BYTE_OFF (WS_PR_BYTE_OFF + NBLOCKS * (int)sizeof(int))

#define LOG2E 1.44269504088896340736f
#define LN2   0.69314718055994530942f

__device__ __forceinline__ float softplus_term(float x) {
    // max(x,0) + log1p(exp(-|x|)) = max(x,0) + ln2 * log2(1 + exp2(-|x| * log2e))
    float a = fabsf(x);
    float t = __builtin_amdgcn_exp2f(-a * LOG2E);   // v_exp_f32
    float l = __builtin_amdgcn_logf(1.0f + t);      // v_log_f32 (log2)
    return fmaxf(x, 0.0f) + LN2 * l;
}

__global__ __launch_bounds__(NTHREADS) void pil_main(
    const float* __restrict__ logits,
    const float* __restrict__ mask,
    double* __restrict__ partial,
    int* __restrict__ pc, int* __restrict__ pr, int* __restrict__ pcol)
{
    const int blk      = blockIdx.x;
    const int slice    = blk / BLOCKS_PER_SLICE;
    const int subchunk = blk % BLOCKS_PER_SLICE;
    const int chunkStartInSlice = subchunk * CHUNK;
    const long long base = (long long)slice * SLICE_ELEMS + chunkStartInSlice;
    const int tid = threadIdx.x;

    const float4* m4 = reinterpret_cast<const float4*>(mask + base);
    const float4* x4 = reinterpret_cast<const float4*>(logits + base);

    int    c_loc = 0, r_loc = 0, col_loc = 0;
    double s_loc = 0.0;

    // CHUNK/4 = 4096 float4 per block; unroll x4: 8 float4 loads in flight
    // (4096 / (4*256) = exactly 4 outer iterations)
    for (int i0 = tid; i0 < CHUNK / 4; i0 += 4 * NTHREADS) {
        float4 ma = m4[i0];
        float4 mb = m4[i0 + NTHREADS];
        float4 mc = m4[i0 + 2 * NTHREADS];
        float4 md = m4[i0 + 3 * NTHREADS];
        float4 xa = x4[i0];
        float4 xb = x4[i0 + NTHREADS];
        float4 xc = x4[i0 + 2 * NTHREADS];
        float4 xd = x4[i0 + 3 * NTHREADS];

        #pragma unroll
        for (int u = 0; u < 4; ++u) {
            float4 m = (u == 0) ? ma : (u == 1) ? mb : (u == 2) ? mc : md;
            float4 x = (u == 0) ? xa : (u == 1) ? xb : (u == 2) ? xc : xd;
            int i = i0 + u * NTHREADS;
            int eInSlice = chunkStartInSlice + i * 4;   // first of the 4 elements
            int row = eInSlice >> 9;                    // /512 (same row for all 4)
            int col = eInSlice & 511;

            int m0 = (m.x != 0.0f);
            int m1 = (m.y != 0.0f);
            int m2 = (m.z != 0.0f);
            int m3 = (m.w != 0.0f);
            int msum = m0 + m1 + m2 + m3;
            c_loc   += msum;
            r_loc   += row * msum;
            col_loc += col * msum + m1 + 2 * m2 + 3 * m3;

            float f = softplus_term(x.x) + softplus_term(x.y)
                    + softplus_term(x.z) + softplus_term(x.w);
            s_loc += (double)f;
        }
    }

    // wave-level reduce (64 lanes)
    for (int off = 32; off > 0; off >>= 1) {
        c_loc   += __shfl_down(c_loc,   off);
        r_loc   += __shfl_down(r_loc,   off);
        col_loc += __shfl_down(col_loc, off);
        s_loc   += __shfl_down(s_loc,   off);
    }

    __shared__ int    sc[NTHREADS / 64], sr[NTHREADS / 64], scol[NTHREADS / 64];
    __shared__ double sd[NTHREADS / 64];
    const int wave = tid >> 6;
    const int lane = tid & 63;
    if (lane == 0) { sc[wave] = c_loc; sr[wave] = r_loc; scol[wave] = col_loc; sd[wave] = s_loc; }
    __syncthreads();

    if (tid == 0) {
        int    bc = 0, br = 0, bcol = 0;
        double bs = 0.0;
        #pragma unroll
        for (int w = 0; w < NTHREADS / 64; ++w) { bc += sc[w]; br += sr[w]; bcol += scol[w]; bs += sd[w]; }
        pc[blk]      = bc;
        pr[blk]      = br;
        pcol[blk]    = bcol;
        partial[blk] = bs;
    }
}

__global__ __launch_bounds__(FTHREADS) void pil_final(
    const float* __restrict__ logits,
    const double* __restrict__ partial,
    const int* __restrict__ pc, const int* __restrict__ pr, const int* __restrict__ pcol,
    float* __restrict__ out)
{
    __shared__ double sdata[FTHREADS];
    const int tid = threadIdx.x;

    double s = 0.0;
    for (int i = tid; i < NBLOCKS; i += FTHREADS) s += partial[i];

    if (tid < SLICES) {
        int c = 0, r = 0, cl = 0;
        #pragma unroll
        for (int k = 0; k < BLOCKS_PER_SLICE; ++k) {
            int idx = tid * BLOCKS_PER_SLICE + k;
            c  += pc[idx];
            r  += pr[idx];
            cl += pcol[idx];
        }
        if (c > 0) {
            // match reference: f32 divide then truncate toward zero
            int mr = (int)((float)r  / (float)c);
            int mc = (int)((float)cl / (float)c);
            s -= (double)logits[(long long)tid * SLICE_ELEMS + (long long)mr * WW + mc];
        }
    }

    sdata[tid] = s;
    __syncthreads();
    for (int stride = FTHREADS / 2; stride > 0; stride >>= 1) {
        if (tid < stride) sdata[tid] += sdata[tid + stride];
        __syncthreads();
    }
    if (tid == 0) out[0] = (float)(sdata[0] / (double)TOTAL_N);
}

extern "C" void kernel_launch(void* const* d_in, const int* in_sizes, int n_in,
                              void* d_out, int out_size, void* d_ws, size_t ws_size,
                              hipStream_t stream)
{
    const float* logits = (const float*)d_in[0];
    const float* mask   = (const float*)d_in[1];
    float* out = (float*)d_out;

    double* partial = (double*)((char*)d_ws + WS_PARTIAL_OFF);
    int*    pc      = (int*)((char*)d_ws + WS_PC_BYTE_OFF);
    int*    pr      = (int*)((char*)d_ws + WS_PR_BYTE_OFF);
    int*    pcol    = (int*)((char*)d_ws + WS_PCOL_BYTE_OFF);

    pil_main<<<NBLOCKS, NTHREADS, 0, stream>>>(logits, mask, partial, pc, pr, pcol);
    pil_final<<<1, FTHREADS, 0, stream>>>(logits, partial, pc, pr, pcol, out);
}